// Round 10
// baseline (637.633 us; speedup 1.0000x reference)
//
#include <hip/hip_runtime.h>

// ===========================================================================
// R10: 3-kernel structure (R9 measured ~12.8us per dispatch level — minimize
// levels, recompute instead of synchronize).
//  K1 conv1234_k: 128 blocks; per-block 2x2 splat tile from lowres via LDS
//     halo tiles x1(23x23x8) -> x2(11x11x16) -> x3(5x5x32) -> splat. +LUT.
//  K2 l1locg_k: 128 loc-tile blocks (l1 halo in LDS) + 2 g-chain blocks
//     (g1->g2->fc3->fc4->fc5 per batch, LDS-staged). -> loc, glob.
//  K3 slice_k: per-row block recomputes fusion+pointwise grid cells for its
//     2 y-rows, y-lerps into LDS, then LUT guide + bilinear(x,z) + apply.
// ===========================================================================

#define LUT_NB   512
#define LUT_LO   (-0.25f)
#define LUT_BIN  (1.5f / LUT_NB)
#define LUT_INV  (LUT_NB / 1.5f)

#define WREDUCE(acc) \
    { acc += __shfl_xor(acc, 32, 64); acc += __shfl_xor(acc, 16, 64); \
      acc += __shfl_xor(acc, 8, 64);  acc += __shfl_xor(acc, 4, 64);  \
      acc += __shfl_xor(acc, 2, 64);  acc += __shfl_xor(acc, 1, 64); }

// ---------------------------------------------------------------------------
// K1: fused conv1+conv2+conv3+conv4 (+LUT build in block 0).
// 128 blocks x 512 thr: block = (n, th, tw) over 8x8 tiles of 2x2 splat.
// ---------------------------------------------------------------------------
__global__ void __launch_bounds__(512) conv1234_k(
    const float* __restrict__ lowres,
    const float* __restrict__ sw1, const float* __restrict__ sb1,
    const float* __restrict__ sw2, const float* __restrict__ sb2,
    const float* __restrict__ sw3, const float* __restrict__ sb3,
    const float* __restrict__ sw4, const float* __restrict__ sb4,
    const float* __restrict__ thr, const float* __restrict__ slp,
    float* __restrict__ splat, float2* __restrict__ lut)
{
    __shared__ float s_x1[23 * 23 * 8];    // 16.9KB
    __shared__ float s_x2[11 * 11 * 16];   // 7.7KB
    __shared__ float s_x3[5 * 5 * 32];     // 3.2KB

    const int tid  = threadIdx.x;
    const int n    = blockIdx.x >> 6;
    const int tile = blockIdx.x & 63;
    const int th   = tile >> 3, tw = tile & 7;

    // LUT build (block 0)
    if (blockIdx.x == 0) {
        for (int e = tid; e < 3 * LUT_NB; e += 512) {
            int j = e >> 9;
            int i = e & (LUT_NB - 1);
            float xl = LUT_LO + i * LUT_BIN;
            float xh = xl + LUT_BIN;
            float a = 0.0f, c = 0.0f;
            #pragma unroll
            for (int k = 0; k < 16; ++k) {
                float tt = thr[j * 16 + k], ss = slp[j * 16 + k];
                a = fmaf(ss, fmaxf(xl - tt, 0.0f), a);
                c = fmaf(ss, fmaxf(xh - tt, 0.0f), c);
            }
            lut[e] = make_float2(a, c - a);
        }
    }

    const int b3h = 4 * th - 1, b3w = 4 * tw - 1;
    const int b2h = 8 * th - 3, b2w = 8 * tw - 3;
    const int b1h = 16 * th - 7, b1w = 16 * tw - 7;

    // Phase A: x1 tile 23x23x8 (conv1 from lowres, zero outside domain)
    for (int i = tid; i < 23 * 23 * 8; i += 512) {
        int c = i & 7;
        int pos = i >> 3;
        int lw = pos % 23, lh = pos / 23;
        int gh = b1h + lh, gw = b1w + lw;
        float v = 0.0f;
        if (gh >= 0 && gh < 128 && gw >= 0 && gw < 128) {
            float acc = sb1[c];
            #pragma unroll
            for (int ci = 0; ci < 3; ++ci) {
                const float* ib = lowres + ((size_t)(n * 3 + ci)) * 65536;
                const float* wb = sw1 + ((size_t)c * 3 + ci) * 9;
                #pragma unroll
                for (int kh = 0; kh < 3; ++kh) {
                    int ih = 2 * gh - 1 + kh;
                    if (ih < 0 || ih >= 256) continue;
                    #pragma unroll
                    for (int kw = 0; kw < 3; ++kw) {
                        int iw = 2 * gw - 1 + kw;
                        if (iw < 0 || iw >= 256) continue;
                        acc = fmaf(ib[ih * 256 + iw], wb[kh * 3 + kw], acc);
                    }
                }
            }
            v = fmaxf(acc, 0.0f);
        }
        s_x1[i] = v;
    }
    __syncthreads();

    // Phase B: x2 tile 11x11x16 (conv2 from s_x1)
    for (int i = tid; i < 11 * 11 * 16; i += 512) {
        int c = i & 15;
        int pos = i >> 4;
        int lw = pos % 11, lh = pos / 11;
        int gh = b2h + lh, gw = b2w + lw;
        float v = 0.0f;
        if (gh >= 0 && gh < 64 && gw >= 0 && gw < 64) {
            float acc = sb2[c];
            const float* wb = sw2 + (size_t)c * 72;
            #pragma unroll
            for (int kh = 0; kh < 3; ++kh) {
                #pragma unroll
                for (int kw = 0; kw < 3; ++kw) {
                    const float* xp = &s_x1[((2 * lh + kh) * 23 + 2 * lw + kw) * 8];
                    const float* wp = wb + kh * 3 + kw;
                    #pragma unroll
                    for (int ci = 0; ci < 8; ++ci)
                        acc = fmaf(xp[ci], wp[ci * 9], acc);
                }
            }
            v = fmaxf(acc, 0.0f);
        }
        s_x2[i] = v;
    }
    __syncthreads();

    // Phase C: x3 tile 5x5x32 (conv3 from s_x2)
    for (int i = tid; i < 5 * 5 * 32; i += 512) {
        int c = i & 31;
        int pos = i >> 5;
        int lw = pos % 5, lh = pos / 5;
        int gh = b3h + lh, gw = b3w + lw;
        float v = 0.0f;
        if (gh >= 0 && gh < 32 && gw >= 0 && gw < 32) {
            float acc = sb3[c];
            const float* wb = sw3 + (size_t)c * 144;
            #pragma unroll
            for (int kh = 0; kh < 3; ++kh) {
                #pragma unroll
                for (int kw = 0; kw < 3; ++kw) {
                    const float* xp = &s_x2[((2 * lh + kh) * 11 + 2 * lw + kw) * 16];
                    const float* wp = wb + kh * 3 + kw;
                    #pragma unroll
                    for (int ci = 0; ci < 16; ++ci)
                        acc = fmaf(xp[ci], wp[ci * 9], acc);
                }
            }
            v = fmaxf(acc, 0.0f);
        }
        s_x3[i] = v;
    }
    __syncthreads();

    // Phase D: splat 2x2x64 (conv4 from s_x3) -> global HWC
    if (tid < 256) {
        int c = tid & 63;
        int pos = tid >> 6;
        int lh = pos >> 1, lw = pos & 1;
        int gh = 2 * th + lh, gw = 2 * tw + lw;
        float acc = sb4[c];
        const float* wb = sw4 + (size_t)c * 288;
        #pragma unroll
        for (int kh = 0; kh < 3; ++kh) {
            #pragma unroll
            for (int kw = 0; kw < 3; ++kw) {
                const float* xp = &s_x3[((2 * lh + kh) * 5 + 2 * lw + kw) * 32];
                const float* wp = wb + kh * 3 + kw;
                #pragma unroll
                for (int ci = 0; ci < 32; ++ci)
                    acc = fmaf(xp[ci], wp[ci * 9], acc);
            }
        }
        splat[((size_t)(n * 16 + gh) * 16 + gw) * 64 + c] = fmaxf(acc, 0.0f);
    }
}

// ---------------------------------------------------------------------------
// K2: 130 blocks x 1024 thr.
//  blocks 0..127: loc 2x2 tile (l1 4x4x64 halo in LDS, wave lane=cin)
//  blocks 128,129: per-batch g-chain g1->g2->fc3->fc4->fc5 -> glob
// ---------------------------------------------------------------------------
__global__ void __launch_bounds__(1024) l1locg_k(
    const float* __restrict__ splat,
    const float* __restrict__ lw1, const float* __restrict__ lb1,
    const float* __restrict__ lw2,
    const float* __restrict__ gw1, const float* __restrict__ gb1,
    const float* __restrict__ gw2, const float* __restrict__ gb2,
    const float* __restrict__ fw3, const float* __restrict__ fb3,
    const float* __restrict__ fw4, const float* __restrict__ fb4,
    const float* __restrict__ fw5, const float* __restrict__ fb5,
    float* __restrict__ loc, float* __restrict__ glob)
{
    __shared__ float s_a[4096];   // l1 tile (1024) or g1 (4096)
    __shared__ float s_b[1024];   // g2
    __shared__ float s_f3[256];
    __shared__ float s_f4[128];

    const int lane = threadIdx.x & 63;
    const int wid  = threadIdx.x >> 6;    // 16 waves

    if (blockIdx.x < 128) {
        // ---- loc 2x2 tile ----
        const int n    = blockIdx.x >> 6;
        const int tile = blockIdx.x & 63;
        const int th   = tile >> 3, tw = tile & 7;
        const int bh   = 2 * th - 1, bw = 2 * tw - 1;
        const float* sp = splat + (size_t)n * 16384;

        // Phase A: l1 4x4x64 -> s_a  (wave per output, lane = cin)
        for (int o = wid; o < 1024; o += 16) {
            int co = o & 63;
            int pos = o >> 6;
            int lh = pos >> 2, lw_ = pos & 3;
            int gh = bh + lh, gw = bw + lw_;
            float v = 0.0f;
            if (gh >= 0 && gh < 16 && gw >= 0 && gw < 16) {
                const float* wb = lw1 + ((size_t)co * 64 + lane) * 9;
                float acc = 0.0f;
                #pragma unroll
                for (int kh = 0; kh < 3; ++kh) {
                    int ih = gh - 1 + kh;
                    if (ih < 0 || ih >= 16) continue;
                    #pragma unroll
                    for (int kw = 0; kw < 3; ++kw) {
                        int iw = gw - 1 + kw;
                        if (iw < 0 || iw >= 16) continue;
                        acc = fmaf(sp[((size_t)ih * 16 + iw) * 64 + lane],
                                   wb[kh * 3 + kw], acc);
                    }
                }
                WREDUCE(acc);
                v = fmaxf(acc + lb1[co], 0.0f);
            }
            if (lane == 0) s_a[pos * 64 + co] = v;
        }
        __syncthreads();

        // Phase B: loc 2x2x64 from s_a (zero-pad already in tile)
        for (int o = wid; o < 256; o += 16) {
            int co = o & 63;
            int pos = o >> 6;
            int lh = pos >> 1, lw_ = pos & 1;
            const float* wb = lw2 + ((size_t)co * 64 + lane) * 9;
            float acc = 0.0f;
            #pragma unroll
            for (int kh = 0; kh < 3; ++kh) {
                #pragma unroll
                for (int kw = 0; kw < 3; ++kw) {
                    acc = fmaf(s_a[((lh + kh) * 4 + lw_ + kw) * 64 + lane],
                               wb[kh * 3 + kw], acc);
                }
            }
            WREDUCE(acc);
            if (lane == 0)
                loc[((size_t)(n * 16 + 2 * th + lh) * 16 + 2 * tw + lw_) * 64 + co] = acc;
        }
    } else {
        // ---- g-chain for batch n ----
        const int n = blockIdx.x - 128;
        const float* sp = splat + (size_t)n * 16384;

        // g1: 8x8x64
        for (int o = wid; o < 4096; o += 16) {
            int co = o & 63;
            int pos = o >> 6;
            int oh = pos >> 3, ow = pos & 7;
            const float* wb = gw1 + ((size_t)co * 64 + lane) * 9;
            float acc = 0.0f;
            #pragma unroll
            for (int kh = 0; kh < 3; ++kh) {
                int ih = 2 * oh - 1 + kh;
                if (ih < 0 || ih >= 16) continue;
                #pragma unroll
                for (int kw = 0; kw < 3; ++kw) {
                    int iw = 2 * ow - 1 + kw;
                    if (iw < 0 || iw >= 16) continue;
                    acc = fmaf(sp[((size_t)ih * 16 + iw) * 64 + lane],
                               wb[kh * 3 + kw], acc);
                }
            }
            WREDUCE(acc);
            if (lane == 0) s_a[pos * 64 + co] = fmaxf(acc + gb1[co], 0.0f);
        }
        __syncthreads();

        // g2: 4x4x64 from s_a
        for (int o = wid; o < 1024; o += 16) {
            int co = o & 63;
            int pos = o >> 6;
            int oh = pos >> 2, ow = pos & 3;
            const float* wb = gw2 + ((size_t)co * 64 + lane) * 9;
            float acc = 0.0f;
            #pragma unroll
            for (int kh = 0; kh < 3; ++kh) {
                int ih = 2 * oh - 1 + kh;
                if (ih < 0 || ih >= 8) continue;
                #pragma unroll
                for (int kw = 0; kw < 3; ++kw) {
                    int iw = 2 * ow - 1 + kw;
                    if (iw < 0 || iw >= 8) continue;
                    acc = fmaf(s_a[(ih * 8 + iw) * 64 + lane], wb[kh * 3 + kw], acc);
                }
            }
            WREDUCE(acc);
            if (lane == 0) s_b[pos * 64 + co] = fmaxf(acc + gb2[co], 0.0f);
        }
        __syncthreads();

        // fc3: 256 outputs (g2 HWC -> CHW permute)
        for (int o = wid; o < 256; o += 16) {
            const float* wb = fw3 + (size_t)o * 1024;
            float acc = 0.0f;
            #pragma unroll
            for (int i = 0; i < 16; ++i) {
                int j = lane + i * 64;
                acc = fmaf(s_b[(j & 15) * 64 + (j >> 4)], wb[j], acc);
            }
            WREDUCE(acc);
            if (lane == 0) s_f3[o] = fmaxf(acc + fb3[o], 0.0f);
        }
        __syncthreads();

        // fc4: 128
        for (int o = wid; o < 128; o += 16) {
            const float* wb = fw4 + (size_t)o * 256;
            float acc = 0.0f;
            #pragma unroll
            for (int j = 0; j < 4; ++j)
                acc = fmaf(s_f3[lane + j * 64], wb[lane + j * 64], acc);
            WREDUCE(acc);
            if (lane == 0) s_f4[o] = fmaxf(acc + fb4[o], 0.0f);
        }
        __syncthreads();

        // fc5: 64 (no relu)
        for (int o = wid; o < 64; o += 16) {
            const float* wb = fw5 + (size_t)o * 128;
            float acc = 0.0f;
            #pragma unroll
            for (int j = 0; j < 2; ++j)
                acc = fmaf(s_f4[lane + j * 64], wb[lane + j * 64], acc);
            WREDUCE(acc);
            if (lane == 0) glob[(size_t)n * 64 + o] = acc + fb5[o];
        }
    }
}

// ---------------------------------------------------------------------------
// K3: slice, one block per row (256 thr x 4 px). Recomputes its 2 y-rows of
// the fused grid (fusion+pointwise) from loc+glob+pw, y-lerps into LDS, then
// LUT guide + bilinear(x,z) + affine apply.
// ---------------------------------------------------------------------------
__global__ void __launch_bounds__(256) slice_k(
    const float* __restrict__ fullres,
    const float* __restrict__ loc, const float* __restrict__ glob,
    const float* __restrict__ pw, const float* __restrict__ pb,
    const float2* __restrict__ lutg,
    const float* __restrict__ M, const float* __restrict__ Mb,
    const float* __restrict__ gbias,
    float* __restrict__ out)
{
    const int W = 1024, H = 1024;
    __shared__ float  ly[1536];            // [z][x][c] = [8][16][12]
    __shared__ float  gtmp[2 * 16 * 96];   // [yi][x][co]
    __shared__ float2 lutS[3 * LUT_NB];

    int h = blockIdx.x & 1023;
    int n = blockIdx.x >> 10;

    float iy = fminf(fmaxf((float)h * (16.0f / (H - 1)) - 0.5f, 0.0f), 15.0f);
    float y0f = floorf(iy);
    float wy  = iy - y0f;
    int y0 = (int)y0f, y1 = min(y0 + 1, 15);

    // load LUT
    for (int i = threadIdx.x; i < 3 * LUT_NB; i += 256)
        lutS[i] = lutg[i];

    // Stage 1: fused grid values for rows y0,y1: thread -> (pos, co-group)
    {
        int t   = threadIdx.x;
        int pos = t >> 3;                   // 32 = 2yi x 16x
        int grp = t & 7;                    // 12 co each
        int yi  = pos >> 4;
        int x   = pos & 15;
        int y   = yi ? y1 : y0;

        // fusion vector (64)
        float fus[64];
        const float4* lp = (const float4*)(loc + ((size_t)(n * 16 + y) * 16 + x) * 64);
        const float4* gp = (const float4*)(glob + (size_t)n * 64);
        #pragma unroll
        for (int i = 0; i < 16; ++i) {
            float4 l = lp[i], g = gp[i];
            fus[4 * i + 0] = fmaxf(l.x + g.x, 0.0f);
            fus[4 * i + 1] = fmaxf(l.y + g.y, 0.0f);
            fus[4 * i + 2] = fmaxf(l.z + g.z, 0.0f);
            fus[4 * i + 3] = fmaxf(l.w + g.w, 0.0f);
        }
        #pragma unroll
        for (int k = 0; k < 12; ++k) {
            int co = grp * 12 + k;
            const float* wp = pw + (size_t)co * 64;
            float acc = pb[co];
            #pragma unroll
            for (int i = 0; i < 64; ++i)
                acc = fmaf(fus[i], wp[i], acc);
            gtmp[(yi * 16 + x) * 96 + co] = acc;
        }
    }
    __syncthreads();

    // Stage 2: y-lerp into ly[z][x][c], co = c*8+z
    for (int i = threadIdx.x; i < 1536; i += 256) {
        int z   = i / 192;
        int rem = i - z * 192;
        int x   = rem / 12;
        int c   = rem - x * 12;
        int co  = c * 8 + z;
        float a = gtmp[x * 96 + co];
        float b = gtmp[(16 + x) * 96 + co];
        ly[i] = fmaf(wy, b - a, a);
    }
    __syncthreads();

    // hoisted guide params
    float M00 = M[0], M10 = M[3], M20 = M[6];
    float M01 = M[1], M11 = M[4], M21 = M[7];
    float M02 = M[2], M12 = M[5], M22 = M[8];
    float Mb0 = Mb[0], Mb1 = Mb[1], Mb2 = Mb[2];
    float gb  = gbias[0];

    int w0 = (int)threadIdx.x * 4;
    size_t plane = (size_t)H * W;
    size_t base  = (size_t)n * 3 * plane + (size_t)h * W + w0;
    float4 R  = *(const float4*)&fullres[base];
    float4 G  = *(const float4*)&fullres[base + plane];
    float4 Bc = *(const float4*)&fullres[base + 2 * plane];

    const float4* L = (const float4*)ly;

    float4 RR, GG, BB;
    float* rr = &RR.x; float* gg = &GG.x; float* bb = &BB.x;
    const float* rp = &R.x; const float* gp2 = &G.x; const float* bp = &Bc.x;

    #pragma unroll
    for (int p = 0; p < 4; ++p) {
        float r = rp[p], g = gp2[p], bc = bp[p];
        int w = w0 + p;

        float g0 = fmaf(r, M00, fmaf(g, M10, fmaf(bc, M20, Mb0)));
        float g1 = fmaf(r, M01, fmaf(g, M11, fmaf(bc, M21, Mb1)));
        float g2 = fmaf(r, M02, fmaf(g, M12, fmaf(bc, M22, Mb2)));
        float sum = 0.0f;
        {
            float t0 = fminf(fmaxf((g0 - LUT_LO) * LUT_INV, 0.0f), LUT_NB - 1.0f);
            int i0 = (int)t0; float f0 = t0 - (float)i0;
            float2 e0 = lutS[i0];
            sum += fmaf(f0, e0.y, e0.x);
            float t1 = fminf(fmaxf((g1 - LUT_LO) * LUT_INV, 0.0f), LUT_NB - 1.0f);
            int i1 = (int)t1; float f1 = t1 - (float)i1;
            float2 e1 = lutS[LUT_NB + i1];
            sum += fmaf(f1, e1.y, e1.x);
            float t2 = fminf(fmaxf((g2 - LUT_LO) * LUT_INV, 0.0f), LUT_NB - 1.0f);
            int i2 = (int)t2; float f2 = t2 - (float)i2;
            float2 e2 = lutS[2 * LUT_NB + i2];
            sum += fmaf(f2, e2.y, e2.x);
        }
        float guide = fminf(fmaxf(sum * (1.0f / 3.0f) + gb, 0.0f), 1.0f);

        float ix = fminf(fmaxf((float)w * (16.0f / (W - 1)) - 0.5f, 0.0f), 15.0f);
        float iz = fminf(fmaxf(8.0f * guide - 0.5f, 0.0f), 7.0f);
        float x0f = floorf(ix), z0f = floorf(iz);
        float wx = ix - x0f, wz = iz - z0f;
        int x0 = (int)x0f; int x1 = min(x0 + 1, 15);
        int z0 = (int)z0f; int z1 = min(z0 + 1, 7);
        float mx = 1.f - wx, mz = 1.f - wz;

        int n00 = (z0 * 16 + x0) * 3, n01 = (z0 * 16 + x1) * 3;
        int n10 = (z1 * 16 + x0) * 3, n11 = (z1 * 16 + x1) * 3;
        float W00 = mz * mx, W01 = mz * wx, W10 = wz * mx, W11 = wz * wx;

        float4 A0 = {0.f, 0.f, 0.f, 0.f}, A1 = A0, A2 = A0;
        auto nodeacc = [&](int nb, float wt) {
            float4 v0 = L[nb], v1 = L[nb + 1], v2 = L[nb + 2];
            A0.x = fmaf(wt, v0.x, A0.x); A0.y = fmaf(wt, v0.y, A0.y);
            A0.z = fmaf(wt, v0.z, A0.z); A0.w = fmaf(wt, v0.w, A0.w);
            A1.x = fmaf(wt, v1.x, A1.x); A1.y = fmaf(wt, v1.y, A1.y);
            A1.z = fmaf(wt, v1.z, A1.z); A1.w = fmaf(wt, v1.w, A1.w);
            A2.x = fmaf(wt, v2.x, A2.x); A2.y = fmaf(wt, v2.y, A2.y);
            A2.z = fmaf(wt, v2.z, A2.z); A2.w = fmaf(wt, v2.w, A2.w);
        };
        nodeacc(n00, W00);
        nodeacc(n01, W01);
        nodeacc(n10, W10);
        nodeacc(n11, W11);

        rr[p] = fmaf(r, A0.x, fmaf(g, A0.y, fmaf(bc, A0.z, A0.w)));
        gg[p] = fmaf(r, A1.x, fmaf(g, A1.y, fmaf(bc, A1.z, A1.w)));
        bb[p] = fmaf(r, A2.x, fmaf(g, A2.y, fmaf(bc, A2.z, A2.w)));
    }

    *(float4*)&out[base]             = RR;
    *(float4*)&out[base + plane]     = GG;
    *(float4*)&out[base + 2 * plane] = BB;
}

// ---------------------------------------------------------------------------
extern "C" void kernel_launch(void* const* d_in, const int* in_sizes, int n_in,
                              void* d_out, int out_size, void* d_ws, size_t ws_size,
                              hipStream_t stream)
{
    const float* lowres  = (const float*)d_in[0];
    const float* fullres = (const float*)d_in[1];
    const float* sw1 = (const float*)d_in[2];  const float* sb1 = (const float*)d_in[3];
    const float* sw2 = (const float*)d_in[4];  const float* sb2 = (const float*)d_in[5];
    const float* sw3 = (const float*)d_in[6];  const float* sb3 = (const float*)d_in[7];
    const float* sw4 = (const float*)d_in[8];  const float* sb4 = (const float*)d_in[9];
    const float* gw1 = (const float*)d_in[10]; const float* gb1 = (const float*)d_in[11];
    const float* gw2 = (const float*)d_in[12]; const float* gb2 = (const float*)d_in[13];
    const float* fw3 = (const float*)d_in[14]; const float* fb3 = (const float*)d_in[15];
    const float* fw4 = (const float*)d_in[16]; const float* fb4 = (const float*)d_in[17];
    const float* fw5 = (const float*)d_in[18]; const float* fb5 = (const float*)d_in[19];
    const float* lw1 = (const float*)d_in[20]; const float* lb1 = (const float*)d_in[21];
    const float* lw2 = (const float*)d_in[22];
    const float* pw  = (const float*)d_in[23]; const float* pb  = (const float*)d_in[24];
    const float* M   = (const float*)d_in[25]; const float* Mb  = (const float*)d_in[26];
    const float* thr = (const float*)d_in[27]; const float* slp = (const float*)d_in[28];
    const float* gbias = (const float*)d_in[29];

    float* ws    = (float*)d_ws;
    float* splat = ws;             // [2][16][16][64] = 32768
    float* loc   = splat + 32768;  // [2][16][16][64] = 32768
    float* glob  = loc + 32768;    // [2][64]
    float2* lutg = (float2*)(glob + 128);   // [3][512] float2

    conv1234_k<<<128, 512, 0, stream>>>(lowres, sw1, sb1, sw2, sb2, sw3, sb3,
        sw4, sb4, thr, slp, splat, lutg);

    l1locg_k<<<130, 1024, 0, stream>>>(splat, lw1, lb1, lw2, gw1, gb1, gw2, gb2,
        fw3, fb3, fw4, fb4, fw5, fb5, loc, glob);

    slice_k<<<2 * 1024, 256, 0, stream>>>(fullres, loc, glob, pw, pb, lutg,
        M, Mb, gbias, (float*)d_out);
}

// Round 11
// 179.702 us; speedup vs baseline: 3.5483x; 3.5483x over previous
//
#include <hip/hip_runtime.h>

// ===========================================================================
// R11: 6 dispatch levels (R9: each level ~12.8us; R10: never put serial
// chains of wave-reduces in one block — one __shfl_xor-64 reduce ~700cy).
//  L1 conv12_k  (512 blk x 256): conv1+conv2 tile-fused via x1 halo in LDS.
//  L2 conv34_k  (128 blk x 256): conv3+conv4 tile-fused via x3 halo in LDS.
//  L3 l1_g1_k   (10240 blk): wide wave-conv, 1 reduce/wave (R8 verbatim).
//  L4 loc_g2_k  (8704 blk):  wide wave-conv, 1 reduce/wave (R8 verbatim).
//  L5 fcfusion_k (16 blk x 1024): fc3/4/5 thread-per-output (float4 weights,
//     no shuffles) recomputed per block + fusion+pointwise -> gridc.
//  L6 guide_slice_lut_k (2048 blk): LUT guide + y-lerp LDS + bilinear slice.
// ===========================================================================

#define LUT_NB   512
#define LUT_LO   (-0.25f)
#define LUT_BIN  (1.5f / LUT_NB)
#define LUT_INV  (LUT_NB / 1.5f)

// ---------------------------------------------------------------------------
// L1: conv1+conv2 fused. Block = (n, 4x4 x2-tile). x1 halo 9x9x8 in LDS.
// ---------------------------------------------------------------------------
__global__ void __launch_bounds__(256) conv12_k(
    const float* __restrict__ lowres,
    const float* __restrict__ sw1, const float* __restrict__ sb1,
    const float* __restrict__ sw2, const float* __restrict__ sb2,
    const float* __restrict__ thr, const float* __restrict__ slp,
    float* __restrict__ x2, float2* __restrict__ lut)
{
    __shared__ float s_x1[9 * 9 * 8];      // 2.6KB
    const int tid  = threadIdx.x;
    const int n    = blockIdx.x >> 8;
    const int tile = blockIdx.x & 255;
    const int ty   = tile >> 4, tx = tile & 15;

    if (blockIdx.x == 0) {
        for (int e = tid; e < 3 * LUT_NB; e += 256) {
            int j = e >> 9;
            int i = e & (LUT_NB - 1);
            float xl = LUT_LO + i * LUT_BIN;
            float xh = xl + LUT_BIN;
            float a = 0.0f, c = 0.0f;
            #pragma unroll
            for (int k = 0; k < 16; ++k) {
                float tt = thr[j * 16 + k], ss = slp[j * 16 + k];
                a = fmaf(ss, fmaxf(xl - tt, 0.0f), a);
                c = fmaf(ss, fmaxf(xh - tt, 0.0f), c);
            }
            lut[e] = make_float2(a, c - a);
        }
    }

    const int b1h = 8 * ty - 1, b1w = 8 * tx - 1;

    // Phase A: x1 halo 9x9x8 (conv1 from lowres; zero outside domain)
    for (int i = tid; i < 648; i += 256) {
        int c   = i & 7;
        int pos = i >> 3;
        int lw  = pos % 9, lh = pos / 9;
        int gh  = b1h + lh, gw = b1w + lw;
        float v = 0.0f;
        if (gh >= 0 && gh < 128 && gw >= 0 && gw < 128) {
            float acc = sb1[c];
            #pragma unroll
            for (int ci = 0; ci < 3; ++ci) {
                const float* ib = lowres + ((size_t)(n * 3 + ci)) * 65536;
                const float* wb = sw1 + ((size_t)c * 3 + ci) * 9;
                #pragma unroll
                for (int kh = 0; kh < 3; ++kh) {
                    int ih = 2 * gh - 1 + kh;
                    if (ih < 0 || ih >= 256) continue;
                    #pragma unroll
                    for (int kw = 0; kw < 3; ++kw) {
                        int iw = 2 * gw - 1 + kw;
                        if (iw < 0 || iw >= 256) continue;
                        acc = fmaf(ib[ih * 256 + iw], wb[kh * 3 + kw], acc);
                    }
                }
            }
            v = fmaxf(acc, 0.0f);
        }
        s_x1[i] = v;
    }
    __syncthreads();

    // Phase B: x2 4x4x16, thread = (pos, co)
    {
        int co  = tid & 15;
        int pos = tid >> 4;             // 16 positions
        int ooh = pos >> 2, oow = pos & 3;
        int oh  = 4 * ty + ooh, ow = 4 * tx + oow;
        float acc = sb2[co];
        const float* wb = sw2 + (size_t)co * 72;
        #pragma unroll
        for (int kh = 0; kh < 3; ++kh) {
            #pragma unroll
            for (int kw = 0; kw < 3; ++kw) {
                const float* xp = &s_x1[((2 * ooh + kh) * 9 + (2 * oow + kw)) * 8];
                const float* wp = wb + kh * 3 + kw;
                #pragma unroll
                for (int ci = 0; ci < 8; ++ci)
                    acc = fmaf(xp[ci], wp[ci * 9], acc);
            }
        }
        x2[((size_t)(n * 64 + oh) * 64 + ow) * 16 + co] = fmaxf(acc, 0.0f);
    }
}

// ---------------------------------------------------------------------------
// L2: conv3+conv4 fused. Block = (n, 2x2 splat-tile). x3 halo 5x5x32 in LDS.
// ---------------------------------------------------------------------------
__global__ void __launch_bounds__(256) conv34_k(
    const float* __restrict__ x2,
    const float* __restrict__ sw3, const float* __restrict__ sb3,
    const float* __restrict__ sw4, const float* __restrict__ sb4,
    float* __restrict__ splat)
{
    __shared__ float s_x3[5 * 5 * 32];     // 3.2KB
    const int tid  = threadIdx.x;
    const int n    = blockIdx.x >> 6;
    const int tile = blockIdx.x & 63;
    const int ty   = tile >> 3, tx = tile & 7;
    const int b3h  = 4 * ty - 1, b3w = 4 * tx - 1;

    // Phase A: x3 halo 5x5x32 (conv3 from x2 global)
    for (int i = tid; i < 800; i += 256) {
        int c   = i & 31;
        int pos = i >> 5;
        int lw  = pos % 5, lh = pos / 5;
        int gh  = b3h + lh, gw = b3w + lw;
        float v = 0.0f;
        if (gh >= 0 && gh < 32 && gw >= 0 && gw < 32) {
            float acc = sb3[c];
            const float* wb = sw3 + (size_t)c * 144;
            #pragma unroll
            for (int kh = 0; kh < 3; ++kh) {
                int ih = 2 * gh - 1 + kh;
                if (ih < 0 || ih >= 64) continue;
                #pragma unroll
                for (int kw = 0; kw < 3; ++kw) {
                    int iw = 2 * gw - 1 + kw;
                    if (iw < 0 || iw >= 64) continue;
                    const float* xp = &x2[((size_t)(n * 64 + ih) * 64 + iw) * 16];
                    const float* wp = wb + kh * 3 + kw;
                    #pragma unroll
                    for (int ci = 0; ci < 16; ++ci)
                        acc = fmaf(xp[ci], wp[ci * 9], acc);
                }
            }
            v = fmaxf(acc, 0.0f);
        }
        s_x3[i] = v;
    }
    __syncthreads();

    // Phase B: splat 2x2x64, thread = (pos, co)
    {
        int co  = tid & 63;
        int pos = tid >> 6;             // 4 positions
        int ooh = pos >> 1, oow = pos & 1;
        int oh  = 2 * ty + ooh, ow = 2 * tx + oow;
        float acc = sb4[co];
        const float* wb = sw4 + (size_t)co * 288;
        #pragma unroll
        for (int kh = 0; kh < 3; ++kh) {
            #pragma unroll
            for (int kw = 0; kw < 3; ++kw) {
                const float* xp = &s_x3[((2 * ooh + kh) * 5 + (2 * oow + kw)) * 32];
                const float* wp = wb + kh * 3 + kw;
                #pragma unroll
                for (int ci = 0; ci < 32; ++ci)
                    acc = fmaf(xp[ci], wp[ci * 9], acc);
            }
        }
        splat[((size_t)(n * 16 + oh) * 16 + ow) * 64 + co] = fmaxf(acc, 0.0f);
    }
}

// ---------------------------------------------------------------------------
// CIN=64 wave-conv, ONE output per wave (lane = input channel). [R8 verbatim]
// ---------------------------------------------------------------------------
__device__ __forceinline__ void convw64_one(const float* __restrict__ in,
                                            const float* __restrict__ wgt,
                                            const float* __restrict__ bias,
                                            float* __restrict__ out,
                                            int o, int Hin, int Win, int Wout,
                                            int stride, bool relu, int lane)
{
    int co  = o & 63;
    int pix = o >> 6;
    int ow  = pix % Wout;
    int oh  = pix / Wout;
    const float* wb = wgt + ((size_t)co * 64 + lane) * 9;
    float acc = 0.0f;
    #pragma unroll
    for (int kh = 0; kh < 3; ++kh) {
        int ih = oh * stride - 1 + kh;
        if (ih < 0 || ih >= Hin) continue;
        const float* ib = in + ((size_t)ih * Win) * 64 + lane;
        #pragma unroll
        for (int kw = 0; kw < 3; ++kw) {
            int iw = ow * stride - 1 + kw;
            if (iw < 0 || iw >= Win) continue;
            acc = fmaf(ib[(size_t)iw * 64], wb[kh * 3 + kw], acc);
        }
    }
    #pragma unroll
    for (int off = 32; off >= 1; off >>= 1)
        acc += __shfl_xor(acc, off, 64);
    if (lane == 0) {
        if (bias) acc += bias[co];
        if (relu) acc = fmaxf(acc, 0.0f);
        out[o] = acc;
    }
}

// L3: l1 || g1 [R8 verbatim]
__global__ void l1_g1_k(const float* __restrict__ splat,
                        const float* __restrict__ lw1, const float* __restrict__ lb1,
                        const float* __restrict__ gw1, const float* __restrict__ gb1,
                        float* __restrict__ l1, float* __restrict__ g1)
{
    int lane = threadIdx.x & 63;
    int W = (blockIdx.x * blockDim.x + threadIdx.x) >> 6;
    if (W < 32768) {
        int n = W >> 14, o = W & 16383;
        convw64_one(splat + (size_t)n * 16384, lw1, lb1, l1 + (size_t)n * 16384,
                    o, 16, 16, 16, 1, true, lane);
    } else {
        int W2 = W - 32768;
        if (W2 >= 8192) return;
        int n = W2 >> 12, o = W2 & 4095;
        convw64_one(splat + (size_t)n * 16384, gw1, gb1, g1 + (size_t)n * 4096,
                    o, 16, 16, 8, 2, true, lane);
    }
}

// L4: loc || g2 [R8 verbatim]
__global__ void loc_g2_k(const float* __restrict__ l1, const float* __restrict__ lw2,
                         const float* __restrict__ g1, const float* __restrict__ gw2,
                         const float* __restrict__ gb2,
                         float* __restrict__ loc, float* __restrict__ g2)
{
    int lane = threadIdx.x & 63;
    int W = (blockIdx.x * blockDim.x + threadIdx.x) >> 6;
    if (W < 32768) {
        int n = W >> 14, o = W & 16383;
        convw64_one(l1 + (size_t)n * 16384, lw2, nullptr, loc + (size_t)n * 16384,
                    o, 16, 16, 16, 1, false, lane);
    } else {
        int W2 = W - 32768;
        if (W2 >= 2048) return;
        int n = W2 >> 10, o = W2 & 1023;
        convw64_one(g1 + (size_t)n * 4096, gw2, gb2, g2 + (size_t)n * 1024,
                    o, 8, 8, 4, 2, true, lane);
    }
}

// ---------------------------------------------------------------------------
// L5: fc3+fc4+fc5 (thread-per-output, float4 weight loads, NO shuffles;
// recomputed per block — weights L2-hot) + fusion+pointwise -> gridc.
// 16 blocks x 1024 thr; block (n, q): outputs q*3072 .. +3072 of gridc[n].
// ---------------------------------------------------------------------------
__global__ void __launch_bounds__(1024) fcfusion_k(
    const float* __restrict__ g2,
    const float* __restrict__ fw3, const float* __restrict__ fb3,
    const float* __restrict__ fw4, const float* __restrict__ fb4,
    const float* __restrict__ fw5, const float* __restrict__ fb5,
    const float* __restrict__ loc,
    const float* __restrict__ pw, const float* __restrict__ pb,
    float* __restrict__ gridc)
{
    __shared__ float s_g2[1024];   // CHW-permuted
    __shared__ float s_f3[256];
    __shared__ float s_f4[128];
    __shared__ float s_gl[64];

    const int tid = threadIdx.x;
    const int n   = blockIdx.x >> 3;
    const int q   = blockIdx.x & 7;

    // stage g2 permuted: CHW j = c*16+p  <-  HWC p*64+c
    s_g2[tid] = g2[(size_t)n * 1024 + (tid & 15) * 64 + (tid >> 4)];
    __syncthreads();

    // fc3: 256 outputs, thread-per-output, float4 over IN=1024
    if (tid < 256) {
        const float4* wb = (const float4*)(fw3 + (size_t)tid * 1024);
        const float4* ib = (const float4*)s_g2;
        float acc = fb3[tid];
        #pragma unroll 8
        for (int j = 0; j < 256; ++j) {
            float4 w = wb[j], v = ib[j];
            acc = fmaf(v.x, w.x, acc); acc = fmaf(v.y, w.y, acc);
            acc = fmaf(v.z, w.z, acc); acc = fmaf(v.w, w.w, acc);
        }
        s_f3[tid] = fmaxf(acc, 0.0f);
    }
    __syncthreads();

    // fc4: 128 outputs
    if (tid < 128) {
        const float4* wb = (const float4*)(fw4 + (size_t)tid * 256);
        const float4* ib = (const float4*)s_f3;
        float acc = fb4[tid];
        #pragma unroll 8
        for (int j = 0; j < 64; ++j) {
            float4 w = wb[j], v = ib[j];
            acc = fmaf(v.x, w.x, acc); acc = fmaf(v.y, w.y, acc);
            acc = fmaf(v.z, w.z, acc); acc = fmaf(v.w, w.w, acc);
        }
        s_f4[tid] = fmaxf(acc, 0.0f);
    }
    __syncthreads();

    // fc5: 64 outputs (no relu)
    if (tid < 64) {
        const float4* wb = (const float4*)(fw5 + (size_t)tid * 128);
        const float4* ib = (const float4*)s_f4;
        float acc = fb5[tid];
        #pragma unroll 8
        for (int j = 0; j < 32; ++j) {
            float4 w = wb[j], v = ib[j];
            acc = fmaf(v.x, w.x, acc); acc = fmaf(v.y, w.y, acc);
            acc = fmaf(v.z, w.z, acc); acc = fmaf(v.w, w.w, acc);
        }
        s_gl[tid] = acc;
    }
    __syncthreads();

    // fusion + pointwise: 3 outputs per thread
    const float4* gp = (const float4*)s_gl;
    #pragma unroll
    for (int k = 0; k < 3; ++k) {
        int idx = q * 3072 + k * 1024 + tid;     // < 24576
        int c   = idx % 12;
        int zp  = idx / 12;
        int p   = zp & 255;
        int z   = zp >> 8;
        int co  = c * 8 + z;
        const float4* lp = (const float4*)(loc + ((size_t)n * 256 + p) * 64);
        const float4* wp = (const float4*)(pw + (size_t)co * 64);
        float acc = pb[co];
        #pragma unroll
        for (int i = 0; i < 16; ++i) {
            float4 l = lp[i], g = gp[i], w = wp[i];
            acc = fmaf(fmaxf(l.x + g.x, 0.0f), w.x, acc);
            acc = fmaf(fmaxf(l.y + g.y, 0.0f), w.y, acc);
            acc = fmaf(fmaxf(l.z + g.z, 0.0f), w.z, acc);
            acc = fmaf(fmaxf(l.w + g.w, 0.0f), w.w, acc);
        }
        gridc[(size_t)n * 24576 + idx] = acc;
    }
}

// ---------------------------------------------------------------------------
// L6: guide(LUT) + slice + apply, one block per row. [R8 verbatim]
// ---------------------------------------------------------------------------
__global__ void __launch_bounds__(256) guide_slice_lut_k(
    const float* __restrict__ fullres,
    const float* __restrict__ gridc,
    const float2* __restrict__ lutg,
    const float* __restrict__ M, const float* __restrict__ Mb,
    const float* __restrict__ gbias,
    float* __restrict__ out)
{
    const int W = 1024, H = 1024;
    __shared__ float  ly[1536];
    __shared__ float2 lutS[3 * LUT_NB];

    int h = blockIdx.x & 1023;
    int n = blockIdx.x >> 10;

    float iy = fminf(fmaxf((float)h * (16.0f / (H - 1)) - 0.5f, 0.0f), 15.0f);
    float y0f = floorf(iy);
    float wy  = iy - y0f;
    int y0 = (int)y0f, y1 = min(y0 + 1, 15);

    const float* gn = gridc + (size_t)n * 24576;
    for (int i = threadIdx.x; i < 1536; i += 256) {
        int z   = i / 192;
        int rem = i - z * 192;
        float a = gn[z * 3072 + y0 * 192 + rem];
        float b = gn[z * 3072 + y1 * 192 + rem];
        ly[i] = fmaf(wy, b - a, a);
        lutS[i] = lutg[i];
    }
    __syncthreads();

    float M00 = M[0], M10 = M[3], M20 = M[6];
    float M01 = M[1], M11 = M[4], M21 = M[7];
    float M02 = M[2], M12 = M[5], M22 = M[8];
    float Mb0 = Mb[0], Mb1 = Mb[1], Mb2 = Mb[2];
    float gb  = gbias[0];

    int w0 = (int)threadIdx.x * 4;
    size_t plane = (size_t)H * W;
    size_t base  = (size_t)n * 3 * plane + (size_t)h * W + w0;
    float4 R  = *(const float4*)&fullres[base];
    float4 G  = *(const float4*)&fullres[base + plane];
    float4 Bc = *(const float4*)&fullres[base + 2 * plane];

    const float4* L = (const float4*)ly;

    float4 RR, GG, BB;
    float* rr = &RR.x; float* gg = &GG.x; float* bb = &BB.x;
    const float* rp = &R.x; const float* gp2 = &G.x; const float* bp = &Bc.x;

    #pragma unroll
    for (int p = 0; p < 4; ++p) {
        float r = rp[p], g = gp2[p], bc = bp[p];
        int w = w0 + p;

        float g0 = fmaf(r, M00, fmaf(g, M10, fmaf(bc, M20, Mb0)));
        float g1 = fmaf(r, M01, fmaf(g, M11, fmaf(bc, M21, Mb1)));
        float g2 = fmaf(r, M02, fmaf(g, M12, fmaf(bc, M22, Mb2)));
        float sum = 0.0f;
        {
            float t0 = fminf(fmaxf((g0 - LUT_LO) * LUT_INV, 0.0f), LUT_NB - 1.0f);
            int i0 = (int)t0; float f0 = t0 - (float)i0;
            float2 e0 = lutS[i0];
            sum += fmaf(f0, e0.y, e0.x);
            float t1 = fminf(fmaxf((g1 - LUT_LO) * LUT_INV, 0.0f), LUT_NB - 1.0f);
            int i1 = (int)t1; float f1 = t1 - (float)i1;
            float2 e1 = lutS[LUT_NB + i1];
            sum += fmaf(f1, e1.y, e1.x);
            float t2 = fminf(fmaxf((g2 - LUT_LO) * LUT_INV, 0.0f), LUT_NB - 1.0f);
            int i2 = (int)t2; float f2 = t2 - (float)i2;
            float2 e2 = lutS[2 * LUT_NB + i2];
            sum += fmaf(f2, e2.y, e2.x);
        }
        float guide = fminf(fmaxf(sum * (1.0f / 3.0f) + gb, 0.0f), 1.0f);

        float ix = fminf(fmaxf((float)w * (16.0f / (W - 1)) - 0.5f, 0.0f), 15.0f);
        float iz = fminf(fmaxf(8.0f * guide - 0.5f, 0.0f), 7.0f);
        float x0f = floorf(ix), z0f = floorf(iz);
        float wx = ix - x0f, wz = iz - z0f;
        int x0 = (int)x0f; int x1 = min(x0 + 1, 15);
        int z0 = (int)z0f; int z1 = min(z0 + 1, 7);
        float mx = 1.f - wx, mz = 1.f - wz;

        int n00 = (z0 * 16 + x0) * 3, n01 = (z0 * 16 + x1) * 3;
        int n10 = (z1 * 16 + x0) * 3, n11 = (z1 * 16 + x1) * 3;
        float W00 = mz * mx, W01 = mz * wx, W10 = wz * mx, W11 = wz * wx;

        float4 A0 = {0.f, 0.f, 0.f, 0.f}, A1 = A0, A2 = A0;
        auto nodeacc = [&](int nb, float wt) {
            float4 v0 = L[nb], v1 = L[nb + 1], v2 = L[nb + 2];
            A0.x = fmaf(wt, v0.x, A0.x); A0.y = fmaf(wt, v0.y, A0.y);
            A0.z = fmaf(wt, v0.z, A0.z); A0.w = fmaf(wt, v0.w, A0.w);
            A1.x = fmaf(wt, v1.x, A1.x); A1.y = fmaf(wt, v1.y, A1.y);
            A1.z = fmaf(wt, v1.z, A1.z); A1.w = fmaf(wt, v1.w, A1.w);
            A2.x = fmaf(wt, v2.x, A2.x); A2.y = fmaf(wt, v2.y, A2.y);
            A2.z = fmaf(wt, v2.z, A2.z); A2.w = fmaf(wt, v2.w, A2.w);
        };
        nodeacc(n00, W00);
        nodeacc(n01, W01);
        nodeacc(n10, W10);
        nodeacc(n11, W11);

        rr[p] = fmaf(r, A0.x, fmaf(g, A0.y, fmaf(bc, A0.z, A0.w)));
        gg[p] = fmaf(r, A1.x, fmaf(g, A1.y, fmaf(bc, A1.z, A1.w)));
        bb[p] = fmaf(r, A2.x, fmaf(g, A2.y, fmaf(bc, A2.z, A2.w)));
    }

    *(float4*)&out[base]             = RR;
    *(float4*)&out[base + plane]     = GG;
    *(float4*)&out[base + 2 * plane] = BB;
}

// ---------------------------------------------------------------------------
extern "C" void kernel_launch(void* const* d_in, const int* in_sizes, int n_in,
                              void* d_out, int out_size, void* d_ws, size_t ws_size,
                              hipStream_t stream)
{
    const float* lowres  = (const float*)d_in[0];
    const float* fullres = (const float*)d_in[1];
    const float* sw1 = (const float*)d_in[2];  const float* sb1 = (const float*)d_in[3];
    const float* sw2 = (const float*)d_in[4];  const float* sb2 = (const float*)d_in[5];
    const float* sw3 = (const float*)d_in[6];  const float* sb3 = (const float*)d_in[7];
    const float* sw4 = (const float*)d_in[8];  const float* sb4 = (const float*)d_in[9];
    const float* gw1 = (const float*)d_in[10]; const float* gb1 = (const float*)d_in[11];
    const float* gw2 = (const float*)d_in[12]; const float* gb2 = (const float*)d_in[13];
    const float* fw3 = (const float*)d_in[14]; const float* fb3 = (const float*)d_in[15];
    const float* fw4 = (const float*)d_in[16]; const float* fb4 = (const float*)d_in[17];
    const float* fw5 = (const float*)d_in[18]; const float* fb5 = (const float*)d_in[19];
    const float* lw1 = (const float*)d_in[20]; const float* lb1 = (const float*)d_in[21];
    const float* lw2 = (const float*)d_in[22];
    const float* pw  = (const float*)d_in[23]; const float* pb  = (const float*)d_in[24];
    const float* M   = (const float*)d_in[25]; const float* Mb  = (const float*)d_in[26];
    const float* thr = (const float*)d_in[27]; const float* slp = (const float*)d_in[28];
    const float* gbias = (const float*)d_in[29];

    float* ws    = (float*)d_ws;
    float* x2    = ws;             // HWC [2][64][64][16]  = 131072
    float* splat = x2 + 131072;    // HWC [2][16][16][64]  = 32768
    float* g1    = splat + 32768;  // HWC [2][8][8][64]    = 8192
    float* g2    = g1 + 8192;      // HWC [2][4][4][64]    = 2048
    float* l1    = g2 + 2048;      // HWC [2][16][16][64]  = 32768
    float* loc   = l1 + 32768;     // HWC [2][16][16][64]  = 32768
    float* gridc = loc + 32768;    // [2][8][16][16][12]   = 49152
    float2* lutg = (float2*)(gridc + 49152);  // [3][512] float2

    // L1: conv1+conv2 (+LUT)
    conv12_k<<<512, 256, 0, stream>>>(lowres, sw1, sb1, sw2, sb2, thr, slp,
        x2, lutg);
    // L2: conv3+conv4
    conv34_k<<<128, 256, 0, stream>>>(x2, sw3, sb3, sw4, sb4, splat);
    // L3: l1 || g1
    l1_g1_k<<<10240, 256, 0, stream>>>(splat, lw1, lb1, gw1, gb1, l1, g1);
    // L4: loc || g2
    loc_g2_k<<<8704, 256, 0, stream>>>(l1, lw2, g1, gw2, gb2, loc, g2);
    // L5: fc-chain + fusion + pointwise
    fcfusion_k<<<16, 1024, 0, stream>>>(g2, fw3, fb3, fw4, fb4, fw5, fb5,
        loc, pw, pb, gridc);
    // L6: guide + slice + apply
    guide_slice_lut_k<<<2048, 256, 0, stream>>>(fullres, gridc, lutg, M, Mb,
        gbias, (float*)d_out);
}

// Round 12
// 152.801 us; speedup vs baseline: 4.1729x; 1.1761x over previous
//
#include <hip/hip_runtime.h>

// ===========================================================================
// R12: R11 with L5 widened: fcfusion192_k (192 blk x 256 thr, per-block
// fc3/4/5 recompute, thread-per-output, no shuffle chains).
// Lessons ledger: ~12us/dispatch level (R9); never <64 blocks for any level
// (R3/R10/R11); no serial wave-reduce chains (R10); no grid.sync (R7 ~100us).
// ===========================================================================

#define LUT_NB   512
#define LUT_LO   (-0.25f)
#define LUT_BIN  (1.5f / LUT_NB)
#define LUT_INV  (LUT_NB / 1.5f)

// ---------------------------------------------------------------------------
// L1: conv1+conv2 fused. Block = (n, 4x4 x2-tile). x1 halo 9x9x8 in LDS.
// ---------------------------------------------------------------------------
__global__ void __launch_bounds__(256) conv12_k(
    const float* __restrict__ lowres,
    const float* __restrict__ sw1, const float* __restrict__ sb1,
    const float* __restrict__ sw2, const float* __restrict__ sb2,
    const float* __restrict__ thr, const float* __restrict__ slp,
    float* __restrict__ x2, float2* __restrict__ lut)
{
    __shared__ float s_x1[9 * 9 * 8];
    const int tid  = threadIdx.x;
    const int n    = blockIdx.x >> 8;
    const int tile = blockIdx.x & 255;
    const int ty   = tile >> 4, tx = tile & 15;

    if (blockIdx.x == 0) {
        for (int e = tid; e < 3 * LUT_NB; e += 256) {
            int j = e >> 9;
            int i = e & (LUT_NB - 1);
            float xl = LUT_LO + i * LUT_BIN;
            float xh = xl + LUT_BIN;
            float a = 0.0f, c = 0.0f;
            #pragma unroll
            for (int k = 0; k < 16; ++k) {
                float tt = thr[j * 16 + k], ss = slp[j * 16 + k];
                a = fmaf(ss, fmaxf(xl - tt, 0.0f), a);
                c = fmaf(ss, fmaxf(xh - tt, 0.0f), c);
            }
            lut[e] = make_float2(a, c - a);
        }
    }

    const int b1h = 8 * ty - 1, b1w = 8 * tx - 1;

    for (int i = tid; i < 648; i += 256) {
        int c   = i & 7;
        int pos = i >> 3;
        int lw  = pos % 9, lh = pos / 9;
        int gh  = b1h + lh, gw = b1w + lw;
        float v = 0.0f;
        if (gh >= 0 && gh < 128 && gw >= 0 && gw < 128) {
            float acc = sb1[c];
            #pragma unroll
            for (int ci = 0; ci < 3; ++ci) {
                const float* ib = lowres + ((size_t)(n * 3 + ci)) * 65536;
                const float* wb = sw1 + ((size_t)c * 3 + ci) * 9;
                #pragma unroll
                for (int kh = 0; kh < 3; ++kh) {
                    int ih = 2 * gh - 1 + kh;
                    if (ih < 0 || ih >= 256) continue;
                    #pragma unroll
                    for (int kw = 0; kw < 3; ++kw) {
                        int iw = 2 * gw - 1 + kw;
                        if (iw < 0 || iw >= 256) continue;
                        acc = fmaf(ib[ih * 256 + iw], wb[kh * 3 + kw], acc);
                    }
                }
            }
            v = fmaxf(acc, 0.0f);
        }
        s_x1[i] = v;
    }
    __syncthreads();

    {
        int co  = tid & 15;
        int pos = tid >> 4;
        int ooh = pos >> 2, oow = pos & 3;
        int oh  = 4 * ty + ooh, ow = 4 * tx + oow;
        float acc = sb2[co];
        const float* wb = sw2 + (size_t)co * 72;
        #pragma unroll
        for (int kh = 0; kh < 3; ++kh) {
            #pragma unroll
            for (int kw = 0; kw < 3; ++kw) {
                const float* xp = &s_x1[((2 * ooh + kh) * 9 + (2 * oow + kw)) * 8];
                const float* wp = wb + kh * 3 + kw;
                #pragma unroll
                for (int ci = 0; ci < 8; ++ci)
                    acc = fmaf(xp[ci], wp[ci * 9], acc);
            }
        }
        x2[((size_t)(n * 64 + oh) * 64 + ow) * 16 + co] = fmaxf(acc, 0.0f);
    }
}

// ---------------------------------------------------------------------------
// L2: conv3+conv4 fused. Block = (n, 2x2 splat-tile). x3 halo 5x5x32 in LDS.
// ---------------------------------------------------------------------------
__global__ void __launch_bounds__(256) conv34_k(
    const float* __restrict__ x2,
    const float* __restrict__ sw3, const float* __restrict__ sb3,
    const float* __restrict__ sw4, const float* __restrict__ sb4,
    float* __restrict__ splat)
{
    __shared__ float s_x3[5 * 5 * 32];
    const int tid  = threadIdx.x;
    const int n    = blockIdx.x >> 6;
    const int tile = blockIdx.x & 63;
    const int ty   = tile >> 3, tx = tile & 7;
    const int b3h  = 4 * ty - 1, b3w = 4 * tx - 1;

    for (int i = tid; i < 800; i += 256) {
        int c   = i & 31;
        int pos = i >> 5;
        int lw  = pos % 5, lh = pos / 5;
        int gh  = b3h + lh, gw = b3w + lw;
        float v = 0.0f;
        if (gh >= 0 && gh < 32 && gw >= 0 && gw < 32) {
            float acc = sb3[c];
            const float* wb = sw3 + (size_t)c * 144;
            #pragma unroll
            for (int kh = 0; kh < 3; ++kh) {
                int ih = 2 * gh - 1 + kh;
                if (ih < 0 || ih >= 64) continue;
                #pragma unroll
                for (int kw = 0; kw < 3; ++kw) {
                    int iw = 2 * gw - 1 + kw;
                    if (iw < 0 || iw >= 64) continue;
                    const float* xp = &x2[((size_t)(n * 64 + ih) * 64 + iw) * 16];
                    const float* wp = wb + kh * 3 + kw;
                    #pragma unroll
                    for (int ci = 0; ci < 16; ++ci)
                        acc = fmaf(xp[ci], wp[ci * 9], acc);
                }
            }
            v = fmaxf(acc, 0.0f);
        }
        s_x3[i] = v;
    }
    __syncthreads();

    {
        int co  = tid & 63;
        int pos = tid >> 6;
        int ooh = pos >> 1, oow = pos & 1;
        int oh  = 2 * ty + ooh, ow = 2 * tx + oow;
        float acc = sb4[co];
        const float* wb = sw4 + (size_t)co * 288;
        #pragma unroll
        for (int kh = 0; kh < 3; ++kh) {
            #pragma unroll
            for (int kw = 0; kw < 3; ++kw) {
                const float* xp = &s_x3[((2 * ooh + kh) * 5 + (2 * oow + kw)) * 32];
                const float* wp = wb + kh * 3 + kw;
                #pragma unroll
                for (int ci = 0; ci < 32; ++ci)
                    acc = fmaf(xp[ci], wp[ci * 9], acc);
            }
        }
        splat[((size_t)(n * 16 + oh) * 16 + ow) * 64 + co] = fmaxf(acc, 0.0f);
    }
}

// ---------------------------------------------------------------------------
// CIN=64 wave-conv, ONE output per wave (lane = input channel).
// ---------------------------------------------------------------------------
__device__ __forceinline__ void convw64_one(const float* __restrict__ in,
                                            const float* __restrict__ wgt,
                                            const float* __restrict__ bias,
                                            float* __restrict__ out,
                                            int o, int Hin, int Win, int Wout,
                                            int stride, bool relu, int lane)
{
    int co  = o & 63;
    int pix = o >> 6;
    int ow  = pix % Wout;
    int oh  = pix / Wout;
    const float* wb = wgt + ((size_t)co * 64 + lane) * 9;
    float acc = 0.0f;
    #pragma unroll
    for (int kh = 0; kh < 3; ++kh) {
        int ih = oh * stride - 1 + kh;
        if (ih < 0 || ih >= Hin) continue;
        const float* ib = in + ((size_t)ih * Win) * 64 + lane;
        #pragma unroll
        for (int kw = 0; kw < 3; ++kw) {
            int iw = ow * stride - 1 + kw;
            if (iw < 0 || iw >= Win) continue;
            acc = fmaf(ib[(size_t)iw * 64], wb[kh * 3 + kw], acc);
        }
    }
    #pragma unroll
    for (int off = 32; off >= 1; off >>= 1)
        acc += __shfl_xor(acc, off, 64);
    if (lane == 0) {
        if (bias) acc += bias[co];
        if (relu) acc = fmaxf(acc, 0.0f);
        out[o] = acc;
    }
}

// L3: l1 || g1
__global__ void l1_g1_k(const float* __restrict__ splat,
                        const float* __restrict__ lw1, const float* __restrict__ lb1,
                        const float* __restrict__ gw1, const float* __restrict__ gb1,
                        float* __restrict__ l1, float* __restrict__ g1)
{
    int lane = threadIdx.x & 63;
    int W = (blockIdx.x * blockDim.x + threadIdx.x) >> 6;
    if (W < 32768) {
        int n = W >> 14, o = W & 16383;
        convw64_one(splat + (size_t)n * 16384, lw1, lb1, l1 + (size_t)n * 16384,
                    o, 16, 16, 16, 1, true, lane);
    } else {
        int W2 = W - 32768;
        if (W2 >= 8192) return;
        int n = W2 >> 12, o = W2 & 4095;
        convw64_one(splat + (size_t)n * 16384, gw1, gb1, g1 + (size_t)n * 4096,
                    o, 16, 16, 8, 2, true, lane);
    }
}

// L4: loc || g2
__global__ void loc_g2_k(const float* __restrict__ l1, const float* __restrict__ lw2,
                         const float* __restrict__ g1, const float* __restrict__ gw2,
                         const float* __restrict__ gb2,
                         float* __restrict__ loc, float* __restrict__ g2)
{
    int lane = threadIdx.x & 63;
    int W = (blockIdx.x * blockDim.x + threadIdx.x) >> 6;
    if (W < 32768) {
        int n = W >> 14, o = W & 16383;
        convw64_one(l1 + (size_t)n * 16384, lw2, nullptr, loc + (size_t)n * 16384,
                    o, 16, 16, 16, 1, false, lane);
    } else {
        int W2 = W - 32768;
        if (W2 >= 2048) return;
        int n = W2 >> 10, o = W2 & 1023;
        convw64_one(g1 + (size_t)n * 4096, gw2, gb2, g2 + (size_t)n * 1024,
                    o, 8, 8, 4, 2, true, lane);
    }
}

// ---------------------------------------------------------------------------
// L5: fcfusion192_k — 192 blocks x 256 thr (96 per batch item).
// Per block: fc3/fc4/fc5 recompute (thread-per-output, float4, no shuffles;
// ~1MB L2-hot weights), then 256 fusion+pointwise outputs.
// ---------------------------------------------------------------------------
__global__ void __launch_bounds__(256) fcfusion192_k(
    const float* __restrict__ g2,
    const float* __restrict__ fw3, const float* __restrict__ fb3,
    const float* __restrict__ fw4, const float* __restrict__ fb4,
    const float* __restrict__ fw5, const float* __restrict__ fb5,
    const float* __restrict__ loc,
    const float* __restrict__ pw, const float* __restrict__ pb,
    float* __restrict__ gridc)
{
    __shared__ float s_g2[1024];   // CHW-permuted
    __shared__ float s_f3[256];
    __shared__ float s_f4[128];
    __shared__ float s_gl[64];

    const int tid = threadIdx.x;
    const int n   = blockIdx.x / 96;
    const int q   = blockIdx.x % 96;

    // stage g2 permuted: CHW j = c*16+p  <-  HWC p*64+c
    #pragma unroll
    for (int i = tid; i < 1024; i += 256)
        s_g2[i] = g2[(size_t)n * 1024 + (i & 15) * 64 + (i >> 4)];
    __syncthreads();

    // fc3: 256 outputs, thread-per-output, float4 over IN=1024
    {
        const float4* wb = (const float4*)(fw3 + (size_t)tid * 1024);
        const float4* ib = (const float4*)s_g2;
        float acc = fb3[tid];
        #pragma unroll 8
        for (int j = 0; j < 256; ++j) {
            float4 w = wb[j], v = ib[j];
            acc = fmaf(v.x, w.x, acc); acc = fmaf(v.y, w.y, acc);
            acc = fmaf(v.z, w.z, acc); acc = fmaf(v.w, w.w, acc);
        }
        s_f3[tid] = fmaxf(acc, 0.0f);
    }
    __syncthreads();

    // fc4: 128 outputs
    if (tid < 128) {
        const float4* wb = (const float4*)(fw4 + (size_t)tid * 256);
        const float4* ib = (const float4*)s_f3;
        float acc = fb4[tid];
        #pragma unroll 8
        for (int j = 0; j < 64; ++j) {
            float4 w = wb[j], v = ib[j];
            acc = fmaf(v.x, w.x, acc); acc = fmaf(v.y, w.y, acc);
            acc = fmaf(v.z, w.z, acc); acc = fmaf(v.w, w.w, acc);
        }
        s_f4[tid] = fmaxf(acc, 0.0f);
    }
    __syncthreads();

    // fc5: 64 outputs (no relu)
    if (tid < 64) {
        const float4* wb = (const float4*)(fw5 + (size_t)tid * 128);
        const float4* ib = (const float4*)s_f4;
        float acc = fb5[tid];
        #pragma unroll 8
        for (int j = 0; j < 32; ++j) {
            float4 w = wb[j], v = ib[j];
            acc = fmaf(v.x, w.x, acc); acc = fmaf(v.y, w.y, acc);
            acc = fmaf(v.z, w.z, acc); acc = fmaf(v.w, w.w, acc);
        }
        s_gl[tid] = acc;
    }
    __syncthreads();

    // fusion + pointwise: 1 output per thread (q*256+tid < 24576)
    {
        int idx = q * 256 + tid;
        int c   = idx % 12;
        int zp  = idx / 12;
        int p   = zp & 255;
        int z   = zp >> 8;
        int co  = c * 8 + z;
        const float4* lp = (const float4*)(loc + ((size_t)n * 256 + p) * 64);
        const float4* gp = (const float4*)s_gl;
        const float4* wp = (const float4*)(pw + (size_t)co * 64);
        float acc = pb[co];
        #pragma unroll
        for (int i = 0; i < 16; ++i) {
            float4 l = lp[i], g = gp[i], w = wp[i];
            acc = fmaf(fmaxf(l.x + g.x, 0.0f), w.x, acc);
            acc = fmaf(fmaxf(l.y + g.y, 0.0f), w.y, acc);
            acc = fmaf(fmaxf(l.z + g.z, 0.0f), w.z, acc);
            acc = fmaf(fmaxf(l.w + g.w, 0.0f), w.w, acc);
        }
        gridc[(size_t)n * 24576 + idx] = acc;
    }
}

// ---------------------------------------------------------------------------
// L6: guide(LUT) + slice + apply, one block per row.
// ---------------------------------------------------------------------------
__global__ void __launch_bounds__(256) guide_slice_lut_k(
    const float* __restrict__ fullres,
    const float* __restrict__ gridc,
    const float2* __restrict__ lutg,
    const float* __restrict__ M, const float* __restrict__ Mb,
    const float* __restrict__ gbias,
    float* __restrict__ out)
{
    const int W = 1024, H = 1024;
    __shared__ float  ly[1536];
    __shared__ float2 lutS[3 * LUT_NB];

    int h = blockIdx.x & 1023;
    int n = blockIdx.x >> 10;

    float iy = fminf(fmaxf((float)h * (16.0f / (H - 1)) - 0.5f, 0.0f), 15.0f);
    float y0f = floorf(iy);
    float wy  = iy - y0f;
    int y0 = (int)y0f, y1 = min(y0 + 1, 15);

    const float* gn = gridc + (size_t)n * 24576;
    for (int i = threadIdx.x; i < 1536; i += 256) {
        int z   = i / 192;
        int rem = i - z * 192;
        float a = gn[z * 3072 + y0 * 192 + rem];
        float b = gn[z * 3072 + y1 * 192 + rem];
        ly[i] = fmaf(wy, b - a, a);
        lutS[i] = lutg[i];
    }
    __syncthreads();

    float M00 = M[0], M10 = M[3], M20 = M[6];
    float M01 = M[1], M11 = M[4], M21 = M[7];
    float M02 = M[2], M12 = M[5], M22 = M[8];
    float Mb0 = Mb[0], Mb1 = Mb[1], Mb2 = Mb[2];
    float gb  = gbias[0];

    int w0 = (int)threadIdx.x * 4;
    size_t plane = (size_t)H * W;
    size_t base  = (size_t)n * 3 * plane + (size_t)h * W + w0;
    float4 R  = *(const float4*)&fullres[base];
    float4 G  = *(const float4*)&fullres[base + plane];
    float4 Bc = *(const float4*)&fullres[base + 2 * plane];

    const float4* L = (const float4*)ly;

    float4 RR, GG, BB;
    float* rr = &RR.x; float* gg = &GG.x; float* bb = &BB.x;
    const float* rp = &R.x; const float* gp2 = &G.x; const float* bp = &Bc.x;

    #pragma unroll
    for (int p = 0; p < 4; ++p) {
        float r = rp[p], g = gp2[p], bc = bp[p];
        int w = w0 + p;

        float g0 = fmaf(r, M00, fmaf(g, M10, fmaf(bc, M20, Mb0)));
        float g1 = fmaf(r, M01, fmaf(g, M11, fmaf(bc, M21, Mb1)));
        float g2 = fmaf(r, M02, fmaf(g, M12, fmaf(bc, M22, Mb2)));
        float sum = 0.0f;
        {
            float t0 = fminf(fmaxf((g0 - LUT_LO) * LUT_INV, 0.0f), LUT_NB - 1.0f);
            int i0 = (int)t0; float f0 = t0 - (float)i0;
            float2 e0 = lutS[i0];
            sum += fmaf(f0, e0.y, e0.x);
            float t1 = fminf(fmaxf((g1 - LUT_LO) * LUT_INV, 0.0f), LUT_NB - 1.0f);
            int i1 = (int)t1; float f1 = t1 - (float)i1;
            float2 e1 = lutS[LUT_NB + i1];
            sum += fmaf(f1, e1.y, e1.x);
            float t2 = fminf(fmaxf((g2 - LUT_LO) * LUT_INV, 0.0f), LUT_NB - 1.0f);
            int i2 = (int)t2; float f2 = t2 - (float)i2;
            float2 e2 = lutS[2 * LUT_NB + i2];
            sum += fmaf(f2, e2.y, e2.x);
        }
        float guide = fminf(fmaxf(sum * (1.0f / 3.0f) + gb, 0.0f), 1.0f);

        float ix = fminf(fmaxf((float)w * (16.0f / (W - 1)) - 0.5f, 0.0f), 15.0f);
        float iz = fminf(fmaxf(8.0f * guide - 0.5f, 0.0f), 7.0f);
        float x0f = floorf(ix), z0f = floorf(iz);
        float wx = ix - x0f, wz = iz - z0f;
        int x0 = (int)x0f; int x1 = min(x0 + 1, 15);
        int z0 = (int)z0f; int z1 = min(z0 + 1, 7);
        float mx = 1.f - wx, mz = 1.f - wz;

        int n00 = (z0 * 16 + x0) * 3, n01 = (z0 * 16 + x1) * 3;
        int n10 = (z1 * 16 + x0) * 3, n11 = (z1 * 16 + x1) * 3;
        float W00 = mz * mx, W01 = mz * wx, W10 = wz * mx, W11 = wz * wx;

        float4 A0 = {0.f, 0.f, 0.f, 0.f}, A1 = A0, A2 = A0;
        auto nodeacc = [&](int nb, float wt) {
            float4 v0 = L[nb], v1 = L[nb + 1], v2 = L[nb + 2];
            A0.x = fmaf(wt, v0.x, A0.x); A0.y = fmaf(wt, v0.y, A0.y);
            A0.z = fmaf(wt, v0.z, A0.z); A0.w = fmaf(wt, v0.w, A0.w);
            A1.x = fmaf(wt, v1.x, A1.x); A1.y = fmaf(wt, v1.y, A1.y);
            A1.z = fmaf(wt, v1.z, A1.z); A1.w = fmaf(wt, v1.w, A1.w);
            A2.x = fmaf(wt, v2.x, A2.x); A2.y = fmaf(wt, v2.y, A2.y);
            A2.z = fmaf(wt, v2.z, A2.z); A2.w = fmaf(wt, v2.w, A2.w);
        };
        nodeacc(n00, W00);
        nodeacc(n01, W01);
        nodeacc(n10, W10);
        nodeacc(n11, W11);

        rr[p] = fmaf(r, A0.x, fmaf(g, A0.y, fmaf(bc, A0.z, A0.w)));
        gg[p] = fmaf(r, A1.x, fmaf(g, A1.y, fmaf(bc, A1.z, A1.w)));
        bb[p] = fmaf(r, A2.x, fmaf(g, A2.y, fmaf(bc, A2.z, A2.w)));
    }

    *(float4*)&out[base]             = RR;
    *(float4*)&out[base + plane]     = GG;
    *(float4*)&out[base + 2 * plane] = BB;
}

// ---------------------------------------------------------------------------
extern "C" void kernel_launch(void* const* d_in, const int* in_sizes, int n_in,
                              void* d_out, int out_size, void* d_ws, size_t ws_size,
                              hipStream_t stream)
{
    const float* lowres  = (const float*)d_in[0];
    const float* fullres = (const float*)d_in[1];
    const float* sw1 = (const float*)d_in[2];  const float* sb1 = (const float*)d_in[3];
    const float* sw2 = (const float*)d_in[4];  const float* sb2 = (const float*)d_in[5];
    const float* sw3 = (const float*)d_in[6];  const float* sb3 = (const float*)d_in[7];
    const float* sw4 = (const float*)d_in[8];  const float* sb4 = (const float*)d_in[9];
    const float* gw1 = (const float*)d_in[10]; const float* gb1 = (const float*)d_in[11];
    const float* gw2 = (const float*)d_in[12]; const float* gb2 = (const float*)d_in[13];
    const float* fw3 = (const float*)d_in[14]; const float* fb3 = (const float*)d_in[15];
    const float* fw4 = (const float*)d_in[16]; const float* fb4 = (const float*)d_in[17];
    const float* fw5 = (const float*)d_in[18]; const float* fb5 = (const float*)d_in[19];
    const float* lw1 = (const float*)d_in[20]; const float* lb1 = (const float*)d_in[21];
    const float* lw2 = (const float*)d_in[22];
    const float* pw  = (const float*)d_in[23]; const float* pb  = (const float*)d_in[24];
    const float* M   = (const float*)d_in[25]; const float* Mb  = (const float*)d_in[26];
    const float* thr = (const float*)d_in[27]; const float* slp = (const float*)d_in[28];
    const float* gbias = (const float*)d_in[29];

    float* ws    = (float*)d_ws;
    float* x2    = ws;             // HWC [2][64][64][16]  = 131072
    float* splat = x2 + 131072;    // HWC [2][16][16][64]  = 32768
    float* g1    = splat + 32768;  // HWC [2][8][8][64]    = 8192
    float* g2    = g1 + 8192;      // HWC [2][4][4][64]    = 2048
    float* l1    = g2 + 2048;      // HWC [2][16][16][64]  = 32768
    float* loc   = l1 + 32768;     // HWC [2][16][16][64]  = 32768
    float* gridc = loc + 32768;    // [2][8][16][16][12]   = 49152
    float2* lutg = (float2*)(gridc + 49152);

    conv12_k<<<512, 256, 0, stream>>>(lowres, sw1, sb1, sw2, sb2, thr, slp,
        x2, lutg);
    conv34_k<<<128, 256, 0, stream>>>(x2, sw3, sb3, sw4, sb4, splat);
    l1_g1_k<<<10240, 256, 0, stream>>>(splat, lw1, lb1, gw1, gb1, l1, g1);
    loc_g2_k<<<8704, 256, 0, stream>>>(l1, lw2, g1, gw2, gb2, loc, g2);
    fcfusion192_k<<<192, 256, 0, stream>>>(g2, fw3, fb3, fw4, fb4, fw5, fb5,
        loc, pw, pb, gridc);
    guide_slice_lut_k<<<2048, 256, 0, stream>>>(fullres, gridc, lutg, M, Mb,
        gbias, (float*)d_out);
}